// Round 5
// baseline (145.819 us; speedup 1.0000x reference)
//
#include <hip/hip_runtime.h>

// Problem: B=4, A=160000 anchors, G=64 gt boxes.
// outputs (concat flat): labels [B,A] f32, matched_gt_boxes [B,A,4] f32
constexpr int NB = 4;
constexpr int NA = 160000;
constexpr int NG = 64;

// ws layout: float hi[NB*NG]  (memset 0, k1 atomicMax, k2 uniform-reads)
//            float meta[NB*NG*8] = per-gt {x0,y0,x1,y1, garea,0,score,conf_bits}
//            (written by k1 blockIdx.x==0; k2 runs stream-ordered after k1)

// --- exact-rounding helpers -------------------------------------------------
// contract(off): stop fma fusion that would change rounding vs numpy.
__device__ __forceinline__ float box_area(float x0, float y0, float x1, float y1) {
#pragma clang fp contract(off)
    return (x1 - x0) * (y1 - y0);
}

__device__ __forceinline__ void inter_denom(float gx0, float gy0, float gx1, float gy1, float garea,
                                            float ax0, float ay0, float ax1, float ay1, float aarea,
                                            float& inter, float& denom) {
#pragma clang fp contract(off)
    float ltx = fmaxf(gx0, ax0);
    float lty = fmaxf(gy0, ay0);
    float rbx = fminf(gx1, ax1);
    float rby = fminf(gy1, ay1);
    float w = fmaxf(rbx - ltx, 0.0f);
    float h = fmaxf(rby - lty, 0.0f);
    inter = w * h;
    float s = garea + aarea;        // numpy: area_gt + area_anchor
    denom = s - inter;
}

__device__ __forceinline__ float iou_f(float gx0, float gy0, float gx1, float gy1, float garea,
                                       float ax0, float ay0, float ax1, float ay1, float aarea) {
    float inter, denom;
    inter_denom(gx0, gy0, gx1, gy1, garea, ax0, ay0, ax1, ay1, aarea, inter, denom);
    return inter / denom;           // IEEE fp32 divide
}

// exact comparison i1/d1 > i2/d2 (all >= 0, d > 0): fp32 products in f64 are
// exact (24x24 <= 53 bits) -> REAL-number ordering. Rounding is monotone, so
// the real-max pair's fp32 quotient == max of per-pair rounded quotients.
__device__ __forceinline__ bool frac_gt(float i1, float d1, float i2, float d2) {
    return (double)i1 * (double)d2 > (double)i2 * (double)d1;
}

// --- kernel 1: highest IoU per gt -------------------------------------------
// grid (1000, NB), block 256 (4 waves); wave handles 40 anchors, lane g owns
// gt g. FOUR independent running-best chains (anchors i..i+3) break the
// cmp->cndmask serial dependency; merged after the loop (max value is
// order-invariant under the exact comparator, so bits are unchanged).
__global__ __launch_bounds__(256) void k_gt_highest(
        const float* __restrict__ anchors, const float* __restrict__ gts,
        const float* __restrict__ scores, const int* __restrict__ confs,
        float* __restrict__ ws) {
    const int b = blockIdx.y;
    const int lane = threadIdx.x & 63;
    const int wid = __builtin_amdgcn_readfirstlane(threadIdx.x >> 6);

    const float4* __restrict__ gt4 = reinterpret_cast<const float4*>(gts) + b * NG;
    const float4* __restrict__ anc = reinterpret_cast<const float4*>(anchors) + (size_t)b * NA;

    float4 g = gt4[lane];
    float garea = box_area(g.x, g.y, g.z, g.w);

    const int base = blockIdx.x * 160 + wid * 40;
    float bi0 = 0.0f, bd0 = 1.0f, bi1 = 0.0f, bd1 = 1.0f;
    float bi2 = 0.0f, bd2 = 1.0f, bi3 = 0.0f, bd3 = 1.0f;
#pragma unroll
    for (int i = 0; i < 40; i += 4) {
        // 4 consecutive anchors: 256 B uniform -> batched s_load_dwordx16
        float4 a0 = anc[base + i];
        float4 a1 = anc[base + i + 1];
        float4 a2 = anc[base + i + 2];
        float4 a3 = anc[base + i + 3];
        float in0, dn0, in1, dn1, in2, dn2, in3, dn3;
        inter_denom(g.x, g.y, g.z, g.w, garea, a0.x, a0.y, a0.z, a0.w,
                    box_area(a0.x, a0.y, a0.z, a0.w), in0, dn0);
        inter_denom(g.x, g.y, g.z, g.w, garea, a1.x, a1.y, a1.z, a1.w,
                    box_area(a1.x, a1.y, a1.z, a1.w), in1, dn1);
        inter_denom(g.x, g.y, g.z, g.w, garea, a2.x, a2.y, a2.z, a2.w,
                    box_area(a2.x, a2.y, a2.z, a2.w), in2, dn2);
        inter_denom(g.x, g.y, g.z, g.w, garea, a3.x, a3.y, a3.z, a3.w,
                    box_area(a3.x, a3.y, a3.z, a3.w), in3, dn3);
        if (frac_gt(in0, dn0, bi0, bd0)) { bi0 = in0; bd0 = dn0; }
        if (frac_gt(in1, dn1, bi1, bd1)) { bi1 = in1; bd1 = dn1; }
        if (frac_gt(in2, dn2, bi2, bd2)) { bi2 = in2; bd2 = dn2; }
        if (frac_gt(in3, dn3, bi3, bd3)) { bi3 = in3; bd3 = dn3; }
    }
    // merge the 4 chains (value-only max: order-invariant)
    if (frac_gt(bi1, bd1, bi0, bd0)) { bi0 = bi1; bd0 = bd1; }
    if (frac_gt(bi3, bd3, bi2, bd2)) { bi2 = bi3; bd2 = bd3; }
    if (frac_gt(bi2, bd2, bi0, bd0)) { bi0 = bi2; bd0 = bd2; }

    __shared__ float pi[4][NG], pd[4][NG];
    pi[wid][lane] = bi0;
    pd[wid][lane] = bd0;
    __syncthreads();
    if (threadIdx.x < NG) {
        float ci = pi[0][threadIdx.x], cd = pd[0][threadIdx.x];
#pragma unroll
        for (int wv = 1; wv < 4; ++wv) {
            float ni = pi[wv][threadIdx.x], nd = pd[wv][threadIdx.x];
            if (frac_gt(ni, nd, ci, cd)) { ci = ni; cd = nd; }
        }
        float m = ci / cd;                          // single IEEE divide
        // IoU >= 0: float order == int order of bits
        atomicMax(reinterpret_cast<int*>(&ws[b * NG + threadIdx.x]),
                  __float_as_int(m));
    }

    // block x==0 also publishes the per-gt meta table for k2
    if (blockIdx.x == 0 && threadIdx.x < NG) {
        const int gi = threadIdx.x;
        float4 gv = gt4[gi];
        float ga = box_area(gv.x, gv.y, gv.z, gv.w);
        float4* meta4 = reinterpret_cast<float4*>(ws + NB * NG) + (b * NG + gi) * 2;
        meta4[0] = gv;
        meta4[1] = make_float4(ga, 0.0f, scores[b * NG + gi],
                               __int_as_float(confs[b * NG + gi]));
    }
}

// --- kernel 2: per-anchor match + labels + matched boxes --------------------
// grid (625, NB), block 256, one anchor/thread. Inner loop reads gt meta + hi
// with UNIFORM global loads (-> s_load, constant cache): zero LDS issue in the
// hot loop (R2-R4 were ds_read-issue-bound: b128+b64 per gt x 4 waves/CU
// ~72 cy vs ~44 cy VALU). LDS only for the one-time epilogue gather.
__global__ __launch_bounds__(256) void k_assign(
        const float* __restrict__ anchors, const float* __restrict__ ws,
        float* __restrict__ labels_out, float4* __restrict__ boxes_out) {
    const int b = blockIdx.y;
    const float* __restrict__ hi = ws + b * NG;
    const float4* __restrict__ meta4 =
        reinterpret_cast<const float4*>(ws + NB * NG) + (size_t)b * NG * 2;

    __shared__ float4 sbox[NG];
    __shared__ float ssc[NG];
    __shared__ int scf[NG];
    if (threadIdx.x < NG) {
        float4 mA = meta4[threadIdx.x * 2];
        float4 mB = meta4[threadIdx.x * 2 + 1];
        sbox[threadIdx.x] = mA;
        ssc[threadIdx.x] = mB.z;
        scf[threadIdx.x] = __float_as_int(mB.w);
    }
    __syncthreads();

    const int ai = blockIdx.x * 256 + threadIdx.x;  // 0..159999
    const float4* __restrict__ anc = reinterpret_cast<const float4*>(anchors) + (size_t)b * NA;
    float4 av = anc[ai];
    float aarea = box_area(av.x, av.y, av.z, av.w);

    float best = -1.0f;             // all-zero row -> argmax 0 (first max)
    int   matches = 0;
    bool  lowq = false;
#pragma unroll 8
    for (int g = 0; g < NG; ++g) {
        float4 mA = meta4[g * 2];                   // uniform -> s_load
        float4 mB = meta4[g * 2 + 1];               // uniform -> s_load
        float hg = hi[g];                           // uniform -> s_load
        float v = iou_f(mA.x, mA.y, mA.z, mA.w, mB.x,
                        av.x, av.y, av.z, av.w, aarea);
        if (v > best) { best = v; matches = g; }    // strict > keeps FIRST max
        lowq |= (v == hg);                          // bit-exact equality
    }

    int m    = (best < 0.3f) ? -1 : ((best < 0.7f) ? -2 : matches);
    int midx = lowq ? matches : m;
    int cl   = (midx < 0) ? 0 : midx;

    float4 mg = sbox[cl];
    float  sc = ssc[cl];
    int    cf = scf[cl];

    bool pos = (midx >= 0);
    float lab = pos ? 1.0f : 0.0f;
    lab = fminf(lab, sc);
    if (midx == -1) lab = 0.0f;
    if (midx == -2) lab = -1.0f;
    if (sc < 1.0f && pos) lab = -1.0f;
    if (cf == 0 && pos) lab = -1.0f;

    labels_out[(size_t)b * NA + ai] = lab;
    boxes_out[(size_t)b * NA + ai] = mg;
}

extern "C" void kernel_launch(void* const* d_in, const int* in_sizes, int n_in,
                              void* d_out, int out_size, void* d_ws, size_t ws_size,
                              hipStream_t stream) {
    const float* anchors = (const float*)d_in[0];   // [B,A,4]
    const float* gts     = (const float*)d_in[1];   // [B,G,4]
    const float* scores  = (const float*)d_in[2];   // [B,G]
    const int*   confs   = (const int*)d_in[3];     // [B,G]

    float* labels_out = (float*)d_out;                              // [B,A]
    float4* boxes_out = (float4*)((float*)d_out + (size_t)NB * NA); // [B,A,4]
    float* ws = (float*)d_ws;

    // zero only hi[NB*NG]; meta is fully overwritten by k1 block-x0
    hipMemsetAsync(d_ws, 0, (size_t)NB * NG * sizeof(float), stream);

    dim3 g1(1000, NB), g2(625, NB), blk(256);
    k_gt_highest<<<g1, blk, 0, stream>>>(anchors, gts, scores, confs, ws);
    k_assign<<<g2, blk, 0, stream>>>(anchors, ws, labels_out, boxes_out);
}